// Round 4
// baseline (30270.963 us; speedup 1.0000x reference)
//
#include <hip/hip_runtime.h>
#include <hip/hip_bf16.h>
#include <hip/hip_cooperative_groups.h>

namespace cg = cooperative_groups;

#define B_   256
#define T_   64
#define OBS_ 1024
#define ACT_ 6
#define STO_ 32
#define HID_ 1024
#define DET_ 1024
#define NTH  262144      // 256 blocks * 1024 threads
#define WLDS_BYTES 131072

using bf16 = __bf16;
typedef __attribute__((ext_vector_type(8))) __bf16 bf16x8;
typedef __attribute__((ext_vector_type(4))) float f32x4;

struct Params {
  const float *obs, *actions, *eps_post;
  const float *in_w1, *in_b1, *in_w2, *in_b2;
  const float *gru_wih, *gru_whh, *gru_bih, *gru_bhh;
  const float *pr_w1, *pr_b1, *pr_w2, *pr_b2, *pr_mw, *pr_mb, *pr_sw, *pr_sb;
  const float *po_w1, *po_b1, *po_w2, *po_b2, *po_mw, *po_mb, *po_sw, *po_sb;
  float *feat, *pm, *ps, *qm, *qs;
  unsigned *flags;
  bf16 *w_phb, *w_qhb;
  bf16 *x1b, *x2b, *hb, *p1b, *q1b, *p2b, *q2b, *obsb_all;
  float *gh, *q1acc;
};

__device__ __forceinline__ f32x4 MF(bf16x8 a, bf16x8 b, f32x4 c) {
  return __builtin_amdgcn_mfma_f32_16x16x32_bf16(a, b, c, 0, 0, 0);
}

// ---- lightweight grid barrier: release-store own flag, acquire-poll all ----
__device__ __forceinline__ void gbar(unsigned* f, int bid, int tid, unsigned ep) {
  __syncthreads();
  if (tid == 0)
    __hip_atomic_store(&f[bid * 16], ep, __ATOMIC_RELEASE, __HIP_MEMORY_SCOPE_AGENT);
  if (tid < 256) {
    while (__hip_atomic_load(&f[tid * 16], __ATOMIC_ACQUIRE, __HIP_MEMORY_SCOPE_AGENT) < ep) {}
  }
  __syncthreads();
}

// ---- generic per-CU GEMM, W in LDS (swizzled), 16 waves ----
// MT m-tiles on this CU (8 => wave=(mt=wv&7, ng=wv>>3); 16 => wave=mt, ng=0).
// NT n-frags (16 cols each) per wave.
template<int MT, int NT, int RELU, int OUTF32, int ADDACC, int HASBIAS>
__device__ __forceinline__ void gemm16(
    const bf16* __restrict__ A, int lda, int m0cu,
    const char* __restrict__ wlds,
    const float* __restrict__ bias,    // global base, indexed by gcol
    const float* __restrict__ accin,   // [m][1024] fp32, indexed by gcol
    void* __restrict__ out, int ldo, int ncol0) {
  const int tid = threadIdx.x, lane = tid & 63, wv = tid >> 6;
  const int l15 = lane & 15, kg = lane >> 4, s3 = l15 & 7;
  const int mt = (MT == 16) ? wv : (wv & 7);
  const int ng = (MT == 16) ? 0 : (wv >> 3);
  const int nloc = ng * NT * 16;
  const int m0 = m0cu + mt * 16;

  f32x4 acc[NT];
  #pragma unroll
  for (int nf = 0; nf < NT; ++nf) acc[nf] = f32x4{0.f, 0.f, 0.f, 0.f};

  const bf16* __restrict__ ap = A + (size_t)(m0 + l15) * lda + kg * 8;
  const char* wr[NT];
  #pragma unroll
  for (int nf = 0; nf < NT; ++nf)
    wr[nf] = wlds + (nloc + nf * 16 + l15) * 2048;

  #pragma unroll 8
  for (int k0 = 0; k0 < 1024; k0 += 32) {
    bf16x8 af = *(const bf16x8*)(ap + k0);
    const int kc = (k0 >> 3) + kg;
    #pragma unroll
    for (int nf = 0; nf < NT; ++nf) {
      bf16x8 wf = *(const bf16x8*)(wr[nf] + (((kc) ^ s3) << 4));
      acc[nf] = MF(af, wf, acc[nf]);
    }
  }

  #pragma unroll
  for (int nf = 0; nf < NT; ++nf) {
    const int gcol = ncol0 + nloc + nf * 16 + l15;
    const float bv = HASBIAS ? bias[gcol] : 0.f;
    #pragma unroll
    for (int r = 0; r < 4; ++r) {
      const int row = m0 + kg * 4 + r;
      float v = acc[nf][r] + bv;
      if (ADDACC) v += accin[(size_t)row * 1024 + gcol];
      if (RELU) v = fmaxf(v, 0.f);
      const size_t off = (size_t)row * ldo + gcol;
      if (OUTF32) ((float*)out)[off] = v;
      else        ((bf16*)out)[off] = (bf16)v;
    }
  }
}

__global__ __launch_bounds__(1024, 4) void rssm_kern(Params P) {
  extern __shared__ char dynsm[];
  __shared__ float sh2[1160];
  const int tid = threadIdx.x, bid = blockIdx.x;
  const int gt = bid * 1024 + tid;
  const int wv = tid >> 6, lane = tid & 63;
  const int l15 = lane & 15, kg = lane >> 4, s3 = l15 & 7;

  // ---- role decode ----
  // 0:[0,32) in2 m2 | 1:[32,96) wih-fused | 2:[96,144) whh | 3:[144,176) po1obs m2
  // 4:[176,192) po1h | 5:[192,208) pr1 | 6:[208,224) pr2 | 7:[224,256) po2 m2
  int role, slice = 0, mh = 0;
  if (bid < 32)       { role = 0; slice = bid >> 1;          mh = bid & 1; }
  else if (bid < 96)  { role = 1; slice = bid - 32; }
  else if (bid < 144) { role = 2; slice = bid - 96; }
  else if (bid < 176) { role = 3; slice = (bid - 144) >> 1;  mh = (bid - 144) & 1; }
  else if (bid < 192) { role = 4; slice = bid - 176; }
  else if (bid < 208) { role = 5; slice = bid - 192; }
  else if (bid < 224) { role = 6; slice = bid - 208; }
  else                { role = 7; slice = (bid - 224) >> 1;  mh = (bid - 224) & 1; }

  // ---- prologue: weights -> LDS (swizzled) ----
  {
    const float* wsrc; int wstride = 1024, kcol0 = 0, nrows = 64, wihmap = 0;
    switch (role) {
      case 0:  wsrc = P.in_w2;   break;
      case 1:  wsrc = P.gru_wih; nrows = 48; wihmap = 1; break;
      case 2:  wsrc = P.gru_whh; break;
      case 3:  wsrc = P.po_w1;   wstride = 2048; kcol0 = 1024; break;
      case 4:  wsrc = P.po_w1;   wstride = 2048; break;
      case 5:  wsrc = P.pr_w1;   break;
      case 6:  wsrc = P.pr_w2;   break;
      default: wsrc = P.po_w2;   break;
    }
    for (int idx = tid; idx < nrows * 128; idx += 1024) {
      const int row = idx >> 7, kc = idx & 127;
      const int grow = wihmap ? ((row >> 4) * 1024 + slice * 16 + (row & 15))
                              : (slice * 64 + row);
      const float* sp = wsrc + (size_t)grow * wstride + kcol0 + kc * 8;
      bf16x8 v;
      #pragma unroll
      for (int j = 0; j < 8; ++j) v[j] = (bf16)sp[j];
      *(bf16x8*)(dynsm + row * 2048 + ((kc ^ (row & 7)) << 4)) = v;
    }
    // head weights -> bf16 ws
    for (int i = gt; i < STO_ * HID_; i += NTH) {
      P.w_phb[i]               = (bf16)P.pr_mw[i];
      P.w_phb[STO_ * HID_ + i] = (bf16)P.pr_sw[i];
      P.w_qhb[i]               = (bf16)P.po_mw[i];
      P.w_qhb[STO_ * HID_ + i] = (bf16)P.po_sw[i];
    }
    // obs -> bf16, all steps (same linear index)
    for (int i = gt; i < B_ * T_ * OBS_; i += NTH)
      P.obsb_all[i] = (bf16)P.obs[i];
    // state init
    for (int i = gt; i < B_ * HID_; i += NTH) {
      P.x1b[i] = (bf16)fmaxf(P.in_b1[i & (HID_ - 1)], 0.f);   // z0=0, a0=0
      P.hb[i]  = (bf16)0.f;
    }
    if (tid == 0) P.flags[bid * 16] = 0;
  }
  cg::this_grid().sync();

  float hreg[4] = {0.f, 0.f, 0.f, 0.f};   // wih-fused: persistent h (fp32)
  unsigned ep = 0;

  for (int t = 0; t < T_; ++t) {
    // ---- P1: x2 [in2] ; gh [whh] ; q1acc=obs-part+bias [po1obs] ----
    if (role == 0) {
      gemm16<8, 2, 1, 0, 0, 1>(P.x1b, 1024, mh * 128, dynsm, P.in_b2, nullptr,
                               P.x2b, 1024, slice * 64);
    } else if (role == 2) {
      gemm16<16, 4, 0, 1, 0, 1>(P.hb, 1024, 0, dynsm, P.gru_bhh, nullptr,
                                P.gh, 3072, slice * 64);
    } else if (role == 3) {
      gemm16<8, 2, 0, 1, 0, 1>(P.obsb_all + t * 1024, T_ * 1024, mh * 128, dynsm,
                               P.po_b1, nullptr, P.q1acc, 1024, slice * 64);
    }
    gbar(P.flags, bid, tid, ++ep);

    // ---- P2: gi + GRU fused [wih], h kept in registers ----
    if (role == 1) {
      const int mt = wv;
      const bf16* __restrict__ ap = P.x2b + (size_t)(mt * 16 + l15) * 1024 + kg * 8;
      const char* wr0 = dynsm + l15 * 2048;
      f32x4 ar{0.f,0.f,0.f,0.f}, az = ar, an = ar;
      #pragma unroll 8
      for (int k0 = 0; k0 < 1024; k0 += 32) {
        bf16x8 af = *(const bf16x8*)(ap + k0);
        const int kc = (k0 >> 3) + kg;
        const int so = ((kc ^ s3) << 4);
        bf16x8 w0 = *(const bf16x8*)(wr0 + so);
        bf16x8 w1 = *(const bf16x8*)(wr0 + 16 * 2048 + so);
        bf16x8 w2 = *(const bf16x8*)(wr0 + 32 * 2048 + so);
        ar = MF(af, w0, ar); az = MF(af, w1, az); an = MF(af, w2, an);
      }
      const int c = slice * 16 + l15;
      const float bir = P.gru_bih[c], biz = P.gru_bih[1024 + c], bin_ = P.gru_bih[2048 + c];
      #pragma unroll
      for (int r = 0; r < 4; ++r) {
        const int m = mt * 16 + kg * 4 + r;
        const float* ghp = P.gh + (size_t)m * 3072 + c;
        float rr = ar[r] + bir + ghp[0];
        float zz = az[r] + biz + ghp[1024];
        const float hn = ghp[2048];
        rr = 1.f / (1.f + __expf(-rr));
        zz = 1.f / (1.f + __expf(-zz));
        const float nn = tanhf(an[r] + bin_ + rr * hn);
        const float h2 = (1.f - zz) * nn + zz * hreg[r];
        hreg[r] = h2;
        P.hb[(size_t)m * 1024 + c] = (bf16)h2;
        P.feat[((size_t)m * T_ + t) * 1056 + c] = h2;
      }
    }
    gbar(P.flags, bid, tid, ++ep);

    // ---- P3: q1 = relu(q1acc + h@Wh) [po1h] ; p1 [pr1] ----
    if (role == 4) {
      gemm16<16, 4, 1, 0, 1, 0>(P.hb, 1024, 0, dynsm, nullptr, P.q1acc,
                                P.q1b, 1024, slice * 64);
    } else if (role == 5) {
      gemm16<16, 4, 1, 0, 0, 1>(P.hb, 1024, 0, dynsm, P.pr_b1, nullptr,
                                P.p1b, 1024, slice * 64);
    }
    gbar(P.flags, bid, tid, ++ep);

    // ---- P4: q2 [po2] ; p2 [pr2] ----
    if (role == 7) {
      gemm16<8, 2, 1, 0, 0, 1>(P.q1b, 1024, mh * 128, dynsm, P.po_b2, nullptr,
                               P.q2b, 1024, slice * 64);
    } else if (role == 6) {
      gemm16<16, 4, 1, 0, 0, 1>(P.p1b, 1024, 0, dynsm, P.pr_b2, nullptr,
                                P.p2b, 1024, slice * 64);
    }
    gbar(P.flags, bid, tid, ++ep);

    // ---- P5: heads + stats + z + feat_z + next x1 (all CUs; block = m) ----
    {
      const int m = bid;
      const int o = tid >> 3, th = tid & 7;
      const bf16* srcv = ((o < 64) ? P.p2b : P.q2b) + (size_t)m * 1024 + th * 128;
      const bf16* wrp  = ((o < 64) ? (P.w_phb + (size_t)o * 1024)
                                   : (P.w_qhb + (size_t)(o - 64) * 1024)) + th * 128;
      float acc = 0.f;
      #pragma unroll 4
      for (int k = 0; k < 128; k += 8) {
        bf16x8 av = *(const bf16x8*)(srcv + k);
        bf16x8 wv8 = *(const bf16x8*)(wrp + k);
        #pragma unroll
        for (int jj = 0; jj < 8; ++jj) acc = fmaf((float)av[jj], (float)wv8[jj], acc);
      }
      sh2[tid] = acc;
      if (tid < ACT_) sh2[1120 + tid] = P.actions[((size_t)m * T_ + t) * ACT_ + tid];
      __syncthreads();
      if (tid < 128) {
        float v = 0.f;
        #pragma unroll
        for (int j = 0; j < 8; ++j) v += sh2[tid * 8 + j];
        const size_t ob = ((size_t)m * T_ + t) * STO_;
        if (tid < 32) {
          P.pm[ob + tid] = v + P.pr_mb[tid];
        } else if (tid < 64) {
          float x = v + P.pr_sb[tid - 32];
          P.ps[ob + tid - 32] = __expf(fminf(fmaxf(x, -5.f), 2.f));
        } else if (tid < 96) {
          float x = v + P.po_mb[tid - 64];
          P.qm[ob + tid - 64] = x; sh2[1024 + tid - 64] = x;
        } else {
          float x = v + P.po_sb[tid - 96];
          x = __expf(fminf(fmaxf(x, -5.f), 2.f));
          P.qs[ob + tid - 96] = x; sh2[1056 + tid - 96] = x;
        }
      }
      __syncthreads();
      if (tid < STO_) {
        const float z = sh2[1024 + tid] +
                        sh2[1056 + tid] * P.eps_post[((size_t)m * T_ + t) * STO_ + tid];
        sh2[1088 + tid] = z;
        P.feat[((size_t)m * T_ + t) * 1056 + 1024 + tid] = z;
      }
      __syncthreads();
      {
        const int n = tid;
        const float* w = P.in_w1 + (size_t)n * 38;
        float a = P.in_b1[n];
        #pragma unroll
        for (int k = 0; k < STO_; ++k) a = fmaf(sh2[1088 + k], w[k], a);
        #pragma unroll
        for (int k = 0; k < ACT_; ++k) a = fmaf(sh2[1120 + k], w[32 + k], a);
        P.x1b[(size_t)m * 1024 + n] = (bf16)fmaxf(a, 0.f);
      }
    }
    gbar(P.flags, bid, tid, ++ep);
  }
}

extern "C" void kernel_launch(void* const* d_in, const int* in_sizes, int n_in,
                              void* d_out, int out_size, void* d_ws, size_t ws_size,
                              hipStream_t stream) {
  (void)in_sizes; (void)n_in; (void)out_size; (void)ws_size;
  Params P;
  P.obs      = (const float*)d_in[0];
  P.actions  = (const float*)d_in[1];
  P.eps_post = (const float*)d_in[3];   // eps_prior (d_in[2]) unused by the math
  P.in_w1 = (const float*)d_in[4];  P.in_b1 = (const float*)d_in[5];
  P.in_w2 = (const float*)d_in[6];  P.in_b2 = (const float*)d_in[7];
  P.gru_wih = (const float*)d_in[8];  P.gru_whh = (const float*)d_in[9];
  P.gru_bih = (const float*)d_in[10]; P.gru_bhh = (const float*)d_in[11];
  P.pr_w1 = (const float*)d_in[12]; P.pr_b1 = (const float*)d_in[13];
  P.pr_w2 = (const float*)d_in[14]; P.pr_b2 = (const float*)d_in[15];
  P.pr_mw = (const float*)d_in[16]; P.pr_mb = (const float*)d_in[17];
  P.pr_sw = (const float*)d_in[18]; P.pr_sb = (const float*)d_in[19];
  P.po_w1 = (const float*)d_in[20]; P.po_b1 = (const float*)d_in[21];
  P.po_w2 = (const float*)d_in[22]; P.po_b2 = (const float*)d_in[23];
  P.po_mw = (const float*)d_in[24]; P.po_mb = (const float*)d_in[25];
  P.po_sw = (const float*)d_in[26]; P.po_sb = (const float*)d_in[27];

  P.feat = (float*)d_out;
  P.pm = P.feat + (size_t)B_ * T_ * 1056;
  P.ps = P.pm + (size_t)B_ * T_ * STO_;
  P.qm = P.ps + (size_t)B_ * T_ * STO_;
  P.qs = P.qm + (size_t)B_ * T_ * STO_;

  char* wp_ = (char*)d_ws;
  auto carve = [&](size_t bytes) -> void* {
    void* r = (void*)wp_;
    wp_ += (bytes + 255) & ~(size_t)255;
    return r;
  };
  P.flags    = (unsigned*)carve(256 * 16 * sizeof(unsigned));
  P.w_phb    = (bf16*)carve((size_t)64 * HID_ * 2);
  P.w_qhb    = (bf16*)carve((size_t)64 * HID_ * 2);
  P.x1b      = (bf16*)carve((size_t)B_ * HID_ * 2);
  P.x2b      = (bf16*)carve((size_t)B_ * HID_ * 2);
  P.hb       = (bf16*)carve((size_t)B_ * DET_ * 2);
  P.p1b      = (bf16*)carve((size_t)B_ * HID_ * 2);
  P.q1b      = (bf16*)carve((size_t)B_ * HID_ * 2);
  P.p2b      = (bf16*)carve((size_t)B_ * HID_ * 2);
  P.q2b      = (bf16*)carve((size_t)B_ * HID_ * 2);
  P.obsb_all = (bf16*)carve((size_t)B_ * T_ * OBS_ * 2);
  P.gh       = (float*)carve((size_t)B_ * 3 * DET_ * 4);
  P.q1acc    = (float*)carve((size_t)B_ * HID_ * 4);

  void* kp[] = { (void*)&P };
  hipLaunchCooperativeKernel((const void*)rssm_kern, dim3(256), dim3(1024), kp,
                             (unsigned)WLDS_BYTES, stream);
}

// Round 5
// 8599.013 us; speedup vs baseline: 3.5203x; 3.5203x over previous
//
#include <hip/hip_runtime.h>
#include <hip/hip_bf16.h>

#define B_   256
#define T_   64
#define OBS_ 1024
#define ACT_ 6
#define STO_ 32
#define HID_ 1024
#define DET_ 1024

using bf16 = __bf16;
typedef __attribute__((ext_vector_type(8))) __bf16 bf16x8;
typedef __attribute__((ext_vector_type(4))) float f32x4;

__device__ __forceinline__ f32x4 MF(bf16x8 a, bf16x8 b, f32x4 c) {
  return __builtin_amdgcn_mfma_f32_16x16x32_bf16(a, b, c, 0, 0, 0);
}

// ---------------- weight fp32 -> bf16 (row-major, 1024 cols) ----------------
__global__ void k_cvt2(const float* __restrict__ src, bf16* __restrict__ dst, int srcld) {
  const int row = blockIdx.x;
  const float* s = src + (size_t)row * srcld;
  bf16* d = dst + (size_t)row * 1024;
  const int c = threadIdx.x * 4;
  float4 f = *(const float4*)(s + c);
  d[c] = (bf16)f.x; d[c + 1] = (bf16)f.y; d[c + 2] = (bf16)f.z; d[c + 3] = (bf16)f.w;
}

// ---------------- state init ----------------
__global__ void k_init(const float* __restrict__ in_b1, bf16* __restrict__ x1b,
                       bf16* __restrict__ hb, float* __restrict__ hf) {
  const int i = blockIdx.x * 256 + threadIdx.x;      // < 262144
  x1b[i] = (bf16)fmaxf(in_b1[i & 1023], 0.f);        // z0=0, a0=0
  hb[i] = (bf16)0.f;
  hf[i] = 0.f;
}

// ---------------- multi-GEMM: up to 3 sub-GEMMs per dispatch ----------------
// out[m,n] = act( A[m,:]@W[n,:] + bias[n] + acc[m,n] ), K=1024 fixed.
// Block = 256 thr = 4 waves; tile 64m x 64n; tile id: (tile&3)=mtile, (tile>>2)=ntile.
struct GB {
  const void* A;      // bf16 [256,lda]  (f32 if aF32)
  const bf16* W;      // [N,1024] row-major
  const float* bias;  // [N] or null
  const float* acc;   // f32 [256,accStride] addend or null
  bf16* outB;         // [256,N] or null
  float* outF;        // [256,N] or null
  int N, lda, relu, aF32, accStride;
};

__global__ __launch_bounds__(256) void k_mg(GB g0, GB g1, GB g2, int s1, int s2) {
  GB g; int tile;
  if ((int)blockIdx.x < s1)      { g = g0; tile = blockIdx.x; }
  else if ((int)blockIdx.x < s2) { g = g1; tile = blockIdx.x - s1; }
  else                           { g = g2; tile = blockIdx.x - s2; }
  const int tid = threadIdx.x, lane = tid & 63, wv = tid >> 6;
  const int l15 = lane & 15, kg = lane >> 4, kq = kg * 8, rq = kg * 4;
  const int m0 = (tile & 3) * 64 + wv * 16;
  const int n0 = (tile >> 2) * 64;

  f32x4 c0{0.f,0.f,0.f,0.f}, c1 = c0, c2 = c0, c3 = c0;
  const bf16* __restrict__ wp = g.W + (size_t)(n0 + l15) * 1024 + kq;

  if (!g.aF32) {
    const bf16* __restrict__ ap = (const bf16*)g.A + (size_t)(m0 + l15) * g.lda + kq;
    #pragma unroll 4
    for (int k = 0; k < 1024; k += 32) {
      bf16x8 af = *(const bf16x8*)(ap + k);
      c0 = MF(af, *(const bf16x8*)(wp + k             ), c0);
      c1 = MF(af, *(const bf16x8*)(wp + 16 * 1024 + k ), c1);
      c2 = MF(af, *(const bf16x8*)(wp + 32 * 1024 + k ), c2);
      c3 = MF(af, *(const bf16x8*)(wp + 48 * 1024 + k ), c3);
    }
  } else {
    const float* __restrict__ ap = (const float*)g.A + (size_t)(m0 + l15) * g.lda + kq;
    #pragma unroll 2
    for (int k = 0; k < 1024; k += 32) {
      float4 f0 = *(const float4*)(ap + k);
      float4 f1 = *(const float4*)(ap + k + 4);
      bf16x8 af;
      af[0] = (bf16)f0.x; af[1] = (bf16)f0.y; af[2] = (bf16)f0.z; af[3] = (bf16)f0.w;
      af[4] = (bf16)f1.x; af[5] = (bf16)f1.y; af[6] = (bf16)f1.z; af[7] = (bf16)f1.w;
      c0 = MF(af, *(const bf16x8*)(wp + k             ), c0);
      c1 = MF(af, *(const bf16x8*)(wp + 16 * 1024 + k ), c1);
      c2 = MF(af, *(const bf16x8*)(wp + 32 * 1024 + k ), c2);
      c3 = MF(af, *(const bf16x8*)(wp + 48 * 1024 + k ), c3);
    }
  }

  // D: lane l, reg r -> row m0+(l>>4)*4+r, col n0+t2*16+(l&15)
  f32x4 cc[4] = {c0, c1, c2, c3};
  #pragma unroll
  for (int t2 = 0; t2 < 4; ++t2) {
    const int n = n0 + t2 * 16 + l15;
    const float bv = g.bias ? g.bias[n] : 0.f;
    #pragma unroll
    for (int r = 0; r < 4; ++r) {
      const int row = m0 + rq + r;
      float v = cc[t2][r] + bv;
      if (g.acc) v += g.acc[(size_t)row * g.accStride + n];
      if (g.relu) v = fmaxf(v, 0.f);
      if (g.outB) g.outB[(size_t)row * g.N + n] = (bf16)v;
      if (g.outF) g.outF[(size_t)row * g.N + n] = v;
    }
  }
}

// ---------------- gi GEMM + GRU gates fused ----------------
// Block (mt, cs): rows mt*64..+64, gate-cols cs*16..+16 of each r/z/n chunk.
__global__ __launch_bounds__(256) void k_gates(
    const bf16* __restrict__ x2b, const bf16* __restrict__ wihb,
    const float* __restrict__ bih, const float* __restrict__ gh,
    float* __restrict__ hf, bf16* __restrict__ hb, float* __restrict__ feat, int t) {
  const int bid = blockIdx.x;                  // 256 = 4 mtiles x 64 col-slices
  const int mt = bid & 3, cs = bid >> 2;
  const int tid = threadIdx.x, lane = tid & 63, wv = tid >> 6;
  const int l15 = lane & 15, kg = lane >> 4, kq = kg * 8;
  const int m0 = mt * 64 + wv * 16;
  const int c0 = cs * 16;

  f32x4 ar{0.f,0.f,0.f,0.f}, az = ar, an = ar;
  const bf16* __restrict__ ap = x2b + (size_t)(m0 + l15) * 1024 + kq;
  const bf16* __restrict__ wr = wihb + (size_t)(c0 + l15) * 1024 + kq;
  const size_t GOFF = (size_t)1024 * 1024;
  #pragma unroll 4
  for (int k = 0; k < 1024; k += 32) {
    bf16x8 af = *(const bf16x8*)(ap + k);
    ar = MF(af, *(const bf16x8*)(wr + k           ), ar);
    az = MF(af, *(const bf16x8*)(wr + GOFF + k    ), az);
    an = MF(af, *(const bf16x8*)(wr + 2 * GOFF + k), an);
  }
  const int c = c0 + l15;
  const float bir = bih[c], biz = bih[1024 + c], bin_ = bih[2048 + c];
  #pragma unroll
  for (int r = 0; r < 4; ++r) {
    const int m = m0 + kg * 4 + r;
    const float* ghp = gh + (size_t)m * 3072 + c;
    float rr = ar[r] + bir + ghp[0];
    float zz = az[r] + biz + ghp[1024];
    const float hn = ghp[2048];
    rr = 1.f / (1.f + __expf(-rr));
    zz = 1.f / (1.f + __expf(-zz));
    const float nn = tanhf(an[r] + bin_ + rr * hn);
    const float h2 = (1.f - zz) * nn + zz * hf[(size_t)m * 1024 + c];
    hf[(size_t)m * 1024 + c] = h2;
    hb[(size_t)m * 1024 + c] = (bf16)h2;
    feat[((size_t)m * T_ + t) * 1056 + c] = h2;
  }
}

// ---------------- heads (MFMA, N=128) + stats + z + feat_z + next x1 ----------------
__global__ __launch_bounds__(256) void k_headfin(
    const bf16* __restrict__ p2b, const bf16* __restrict__ q2b,
    const bf16* __restrict__ whead,            // [128,1024]: pr_m, pr_s, po_m, po_s
    const float* __restrict__ pr_mb, const float* __restrict__ pr_sb,
    const float* __restrict__ po_mb, const float* __restrict__ po_sb,
    const float* __restrict__ eps, const float* __restrict__ act,
    const float* __restrict__ in_w1, const float* __restrict__ in_b1,
    float* __restrict__ pm, float* __restrict__ ps,
    float* __restrict__ qm, float* __restrict__ qs,
    float* __restrict__ feat, bf16* __restrict__ x1b, int t) {
  __shared__ float hd[16][128];
  __shared__ float zl[16][32];
  __shared__ float al[16][ACT_];
  const int bid = blockIdx.x, m0 = bid * 16;
  const int tid = threadIdx.x, lane = tid & 63, wv = tid >> 6;
  const int l15 = lane & 15, kg = lane >> 4, kq = kg * 8;

  const bf16* __restrict__ A = (wv < 2) ? p2b : q2b;
  const int nb = wv * 32;
  f32x4 c0{0.f,0.f,0.f,0.f}, c1 = c0;
  const bf16* __restrict__ ap = A + (size_t)(m0 + l15) * 1024 + kq;
  const bf16* __restrict__ wp = whead + (size_t)(nb + l15) * 1024 + kq;
  #pragma unroll 4
  for (int k = 0; k < 1024; k += 32) {
    bf16x8 af = *(const bf16x8*)(ap + k);
    c0 = MF(af, *(const bf16x8*)(wp + k            ), c0);
    c1 = MF(af, *(const bf16x8*)(wp + 16 * 1024 + k), c1);
  }
  #pragma unroll
  for (int r = 0; r < 4; ++r) {
    hd[kg * 4 + r][nb + l15]      = c0[r];
    hd[kg * 4 + r][nb + 16 + l15] = c1[r];
  }
  if (tid < 16 * ACT_) {
    const int ml = tid / ACT_, k = tid % ACT_;
    al[ml][k] = act[((size_t)(m0 + ml) * T_ + t) * ACT_ + k];
  }
  __syncthreads();

  #pragma unroll
  for (int rep = 0; rep < 2; ++rep) {
    const int idx = tid + rep * 256;           // 0..511
    const int ml = idx >> 5, j = idx & 31;
    const size_t ob = ((size_t)(m0 + ml) * T_ + t) * STO_ + j;
    const float pmv = hd[ml][j] + pr_mb[j];
    float psv = hd[ml][32 + j] + pr_sb[j];
    psv = __expf(fminf(fmaxf(psv, -5.f), 2.f));
    const float qmv = hd[ml][64 + j] + po_mb[j];
    float qsv = hd[ml][96 + j] + po_sb[j];
    qsv = __expf(fminf(fmaxf(qsv, -5.f), 2.f));
    pm[ob] = pmv; ps[ob] = psv; qm[ob] = qmv; qs[ob] = qsv;
    const float z = qmv + qsv * eps[ob];
    zl[ml][j] = z;
    feat[((size_t)(m0 + ml) * T_ + t) * 1056 + 1024 + j] = z;
  }
  __syncthreads();

  // x1_{t+1} = relu([z,a] @ in_w1^T + b1), K=38 fp32 VALU
  #pragma unroll 4
  for (int rep = 0; rep < 64; ++rep) {
    const int idx = rep * 256 + tid;           // < 16384
    const int ml = idx >> 10, n = idx & 1023;
    const float* w = in_w1 + (size_t)n * 38;
    float a = in_b1[n];
    #pragma unroll
    for (int k = 0; k < STO_; ++k) a = fmaf(zl[ml][k], w[k], a);
    #pragma unroll
    for (int k = 0; k < ACT_; ++k) a = fmaf(al[ml][k], w[32 + k], a);
    x1b[(size_t)(m0 + ml) * 1024 + n] = (bf16)fmaxf(a, 0.f);
  }
}

extern "C" void kernel_launch(void* const* d_in, const int* in_sizes, int n_in,
                              void* d_out, int out_size, void* d_ws, size_t ws_size,
                              hipStream_t stream) {
  (void)in_sizes; (void)n_in; (void)out_size; (void)ws_size;
  const float* obs      = (const float*)d_in[0];
  const float* actions  = (const float*)d_in[1];
  const float* eps_post = (const float*)d_in[3];   // eps_prior unused by the math
  const float* in_w1 = (const float*)d_in[4];
  const float* in_b1 = (const float*)d_in[5];
  const float* in_w2 = (const float*)d_in[6];
  const float* in_b2 = (const float*)d_in[7];
  const float* gru_wih = (const float*)d_in[8];
  const float* gru_whh = (const float*)d_in[9];
  const float* gru_bih = (const float*)d_in[10];
  const float* gru_bhh = (const float*)d_in[11];
  const float* pr_w1 = (const float*)d_in[12];
  const float* pr_b1 = (const float*)d_in[13];
  const float* pr_w2 = (const float*)d_in[14];
  const float* pr_b2 = (const float*)d_in[15];
  const float* pr_mw = (const float*)d_in[16];
  const float* pr_mb = (const float*)d_in[17];
  const float* pr_sw = (const float*)d_in[18];
  const float* pr_sb = (const float*)d_in[19];
  const float* po_w1 = (const float*)d_in[20];
  const float* po_b1 = (const float*)d_in[21];
  const float* po_w2 = (const float*)d_in[22];
  const float* po_b2 = (const float*)d_in[23];
  const float* po_mw = (const float*)d_in[24];
  const float* po_mb = (const float*)d_in[25];
  const float* po_sw = (const float*)d_in[26];
  const float* po_sb = (const float*)d_in[27];

  float* feat = (float*)d_out;
  float* pm = feat + (size_t)B_ * T_ * 1056;
  float* ps = pm + (size_t)B_ * T_ * STO_;
  float* qm = ps + (size_t)B_ * T_ * STO_;
  float* qs = qm + (size_t)B_ * T_ * STO_;

  char* wp_ = (char*)d_ws;
  auto carve = [&](size_t bytes) -> void* {
    void* r = (void*)wp_;
    wp_ += (bytes + 255) & ~(size_t)255;
    return r;
  };
  bf16* w_in2b  = (bf16*)carve((size_t)HID_ * HID_ * 2);
  bf16* w_wihb  = (bf16*)carve((size_t)3 * DET_ * HID_ * 2);
  bf16* w_whhb  = (bf16*)carve((size_t)3 * DET_ * DET_ * 2);
  bf16* w_pr1b  = (bf16*)carve((size_t)HID_ * DET_ * 2);
  bf16* w_pr2b  = (bf16*)carve((size_t)HID_ * HID_ * 2);
  bf16* w_po1hb = (bf16*)carve((size_t)HID_ * DET_ * 2);
  bf16* w_po1ob = (bf16*)carve((size_t)HID_ * OBS_ * 2);
  bf16* w_po2b  = (bf16*)carve((size_t)HID_ * HID_ * 2);
  bf16* w_headb = (bf16*)carve((size_t)128 * HID_ * 2);
  bf16* x1b  = (bf16*)carve((size_t)B_ * HID_ * 2);
  bf16* x2b  = (bf16*)carve((size_t)B_ * HID_ * 2);
  bf16* hb   = (bf16*)carve((size_t)B_ * DET_ * 2);
  bf16* p1b  = (bf16*)carve((size_t)B_ * HID_ * 2);
  bf16* q1b  = (bf16*)carve((size_t)B_ * HID_ * 2);
  bf16* p2b  = (bf16*)carve((size_t)B_ * HID_ * 2);
  bf16* q2b  = (bf16*)carve((size_t)B_ * HID_ * 2);
  float* hf    = (float*)carve((size_t)B_ * DET_ * 4);
  float* gh    = (float*)carve((size_t)B_ * 3 * DET_ * 4);
  float* q1acc = (float*)carve((size_t)B_ * HID_ * 4);

  // ---- prologue: weight conversions + init ----
  k_cvt2<<<dim3(1024), dim3(256), 0, stream>>>(in_w2,   w_in2b, 1024);
  k_cvt2<<<dim3(3072), dim3(256), 0, stream>>>(gru_wih, w_wihb, 1024);
  k_cvt2<<<dim3(3072), dim3(256), 0, stream>>>(gru_whh, w_whhb, 1024);
  k_cvt2<<<dim3(1024), dim3(256), 0, stream>>>(pr_w1,   w_pr1b, 1024);
  k_cvt2<<<dim3(1024), dim3(256), 0, stream>>>(pr_w2,   w_pr2b, 1024);
  k_cvt2<<<dim3(1024), dim3(256), 0, stream>>>(po_w1,        w_po1hb, 2048);
  k_cvt2<<<dim3(1024), dim3(256), 0, stream>>>(po_w1 + 1024, w_po1ob, 2048);
  k_cvt2<<<dim3(1024), dim3(256), 0, stream>>>(po_w2,   w_po2b, 1024);
  k_cvt2<<<dim3(32),   dim3(256), 0, stream>>>(pr_mw, w_headb,              1024);
  k_cvt2<<<dim3(32),   dim3(256), 0, stream>>>(pr_sw, w_headb + 32 * 1024,  1024);
  k_cvt2<<<dim3(32),   dim3(256), 0, stream>>>(po_mw, w_headb + 64 * 1024,  1024);
  k_cvt2<<<dim3(32),   dim3(256), 0, stream>>>(po_sw, w_headb + 96 * 1024,  1024);
  k_init<<<dim3(1024), dim3(256), 0, stream>>>(in_b1, x1b, hb, hf);

  GB dummy = {};
  for (int t = 0; t < T_; ++t) {
    // K1: x2 || gh || q1acc(obs-part, fp32 A on-the-fly)
    GB g_x2  = { x1b, w_in2b, in_b2,   nullptr, x2b, nullptr, 1024, 1024, 1, 0, 0 };
    GB g_gh  = { hb,  w_whhb, gru_bhh, nullptr, nullptr, gh, 3072, 1024, 0, 0, 0 };
    GB g_q1o = { obs + (size_t)t * 1024, w_po1ob, po_b1, nullptr, nullptr, q1acc,
                 1024, T_ * 1024, 0, 1, 0 };
    k_mg<<<dim3(320), dim3(256), 0, stream>>>(g_x2, g_gh, g_q1o, 64, 256);

    // K2: gi + GRU gates -> h, feat_h
    k_gates<<<dim3(256), dim3(256), 0, stream>>>(x2b, w_wihb, gru_bih, gh, hf, hb, feat, t);

    // K3: pr1 || q1 = relu(h@Wh + q1acc)
    GB g_pr1 = { hb, w_pr1b,  pr_b1,  nullptr, p1b, nullptr, 1024, 1024, 1, 0, 0 };
    GB g_q1  = { hb, w_po1hb, nullptr, q1acc,  q1b, nullptr, 1024, 1024, 1, 0, 1024 };
    k_mg<<<dim3(128), dim3(256), 0, stream>>>(g_pr1, g_q1, dummy, 64, 128);

    // K4: pr2 || po2
    GB g_pr2 = { p1b, w_pr2b, pr_b2, nullptr, p2b, nullptr, 1024, 1024, 1, 0, 0 };
    GB g_po2 = { q1b, w_po2b, po_b2, nullptr, q2b, nullptr, 1024, 1024, 1, 0, 0 };
    k_mg<<<dim3(128), dim3(256), 0, stream>>>(g_pr2, g_po2, dummy, 64, 128);

    // K5: heads + stats + z + feat_z + next x1
    k_headfin<<<dim3(16), dim3(256), 0, stream>>>(
        p2b, q2b, w_headb, pr_mb, pr_sb, po_mb, po_sb,
        eps_post, actions, in_w1, in_b1, pm, ps, qm, qs, feat, x1b, t);
  }
}

// Round 6
// 6055.276 us; speedup vs baseline: 4.9991x; 1.4201x over previous
//
#include <hip/hip_runtime.h>
#include <hip/hip_bf16.h>

#define B_   256
#define T_   64
#define OBS_ 1024
#define ACT_ 6
#define STO_ 32
#define HID_ 1024
#define DET_ 1024

using bf16 = __bf16;
typedef __attribute__((ext_vector_type(8))) __bf16 bf16x8;
typedef __attribute__((ext_vector_type(4))) float f32x4;

__device__ __forceinline__ f32x4 MF(bf16x8 a, bf16x8 b, f32x4 c) {
  return __builtin_amdgcn_mfma_f32_16x16x32_bf16(a, b, c, 0, 0, 0);
}

// ---------------- fused weight conversion (single launch) ----------------
struct CvtArgs {
  const float *in_w2, *gru_wih, *gru_whh, *pr_w1, *pr_w2, *po_w1, *po_w2;
  const float *pr_mw, *pr_sw, *po_mw, *po_sw;
  bf16 *w_in2b, *w_wihb, *w_whhb, *w_pr1b, *w_pr2b, *w_po1hb, *w_po1ob, *w_po2b, *w_headb;
};

__global__ void k_cvtall(CvtArgs a) {
  const int row = blockIdx.x;            // 12416 rows total
  const float* src; bf16* dst; int srcld = 1024, off = 0;
  if      (row < 1024)  { src = a.in_w2   + (size_t)row * 1024;          dst = a.w_in2b  + (size_t)row * 1024; }
  else if (row < 4096)  { int r = row - 1024;  src = a.gru_wih + (size_t)r * 1024; dst = a.w_wihb + (size_t)r * 1024; }
  else if (row < 7168)  { int r = row - 4096;  src = a.gru_whh + (size_t)r * 1024; dst = a.w_whhb + (size_t)r * 1024; }
  else if (row < 8192)  { int r = row - 7168;  src = a.pr_w1   + (size_t)r * 1024; dst = a.w_pr1b + (size_t)r * 1024; }
  else if (row < 9216)  { int r = row - 8192;  src = a.pr_w2   + (size_t)r * 1024; dst = a.w_pr2b + (size_t)r * 1024; }
  else if (row < 10240) { int r = row - 9216;  src = a.po_w1   + (size_t)r * 2048; dst = a.w_po1hb + (size_t)r * 1024; }
  else if (row < 11264) { int r = row - 10240; src = a.po_w1   + (size_t)r * 2048 + 1024; dst = a.w_po1ob + (size_t)r * 1024; }
  else if (row < 12288) { int r = row - 11264; src = a.po_w2   + (size_t)r * 1024; dst = a.w_po2b + (size_t)r * 1024; }
  else {
    int r = row - 12288;                 // 0..127 head rows
    const float* hs[4] = { a.pr_mw, a.pr_sw, a.po_mw, a.po_sw };
    src = hs[r >> 5] + (size_t)(r & 31) * 1024;
    dst = a.w_headb + (size_t)r * 1024;
  }
  const int c = threadIdx.x * 4;
  float4 f = *(const float4*)(src + c);
  dst[c] = (bf16)f.x; dst[c + 1] = (bf16)f.y; dst[c + 2] = (bf16)f.z; dst[c + 3] = (bf16)f.w;
}

// ---------------- state init ----------------
__global__ void k_init(const float* __restrict__ in_b1, bf16* __restrict__ x1b,
                       bf16* __restrict__ hb, float* __restrict__ hf) {
  const int i = blockIdx.x * 256 + threadIdx.x;      // < 262144
  x1b[i] = (bf16)fmaxf(in_b1[i & 1023], 0.f);        // z0=0, a0=0
  hb[i] = (bf16)0.f;
  hf[i] = 0.f;
}

// ---------------- batched obs-part of po1 (runs once) ----------------
// q1acc[rb][n] = obs[rb,:]@w_po1ob[n,:] + po_b1[n], rb in [0,16384)
__global__ __launch_bounds__(256) void k_qbatch(
    const float* __restrict__ obs, const bf16* __restrict__ w,
    const float* __restrict__ bias, float* __restrict__ out) {
  const int tid = threadIdx.x, lane = tid & 63, wv = tid >> 6;
  const int l15 = lane & 15, kg = lane >> 4, kq = kg * 8, rq = kg * 4;
  const int m0 = (blockIdx.x & 255) * 64 + wv * 16;
  const int n0 = (blockIdx.x >> 8) * 64;
  f32x4 c0{0.f,0.f,0.f,0.f}, c1 = c0, c2 = c0, c3 = c0;
  const float* __restrict__ ap = obs + (size_t)(m0 + l15) * 1024 + kq;
  const bf16* __restrict__ wp = w + (size_t)(n0 + l15) * 1024 + kq;
  #pragma unroll 2
  for (int k = 0; k < 1024; k += 32) {
    float4 f0 = *(const float4*)(ap + k);
    float4 f1 = *(const float4*)(ap + k + 4);
    bf16x8 af;
    af[0] = (bf16)f0.x; af[1] = (bf16)f0.y; af[2] = (bf16)f0.z; af[3] = (bf16)f0.w;
    af[4] = (bf16)f1.x; af[5] = (bf16)f1.y; af[6] = (bf16)f1.z; af[7] = (bf16)f1.w;
    c0 = MF(af, *(const bf16x8*)(wp + k            ), c0);
    c1 = MF(af, *(const bf16x8*)(wp + 16 * 1024 + k), c1);
    c2 = MF(af, *(const bf16x8*)(wp + 32 * 1024 + k), c2);
    c3 = MF(af, *(const bf16x8*)(wp + 48 * 1024 + k), c3);
  }
  f32x4 cc[4] = {c0, c1, c2, c3};
  #pragma unroll
  for (int t2 = 0; t2 < 4; ++t2) {
    const int n = n0 + t2 * 16 + l15;
    const float bv = bias[n];
    #pragma unroll
    for (int r = 0; r < 4; ++r)
      out[(size_t)(m0 + rq + r) * 1024 + n] = cc[t2][r] + bv;
  }
}

// ---------------- split-K multi-GEMM (per-step workhorse) ----------------
// tile 16m x 64n; 4 waves K-split (256 each, 8 MFMA iters); LDS reduce.
struct GB {
  const bf16* A;      // [256, lda]
  const bf16* W;      // [N, 1024] row-major
  const float* bias;  // [n] or null
  const float* acc;   // f32 addend, row stride accStride, or null
  bf16* outB;         // or null
  float* outF;        // or null
  int N, lda, relu, accStride;
};

__global__ __launch_bounds__(256, 4) void k_mgs(GB g0, GB g1, int s1) {
  GB g; int tile;
  if ((int)blockIdx.x < s1) { g = g0; tile = blockIdx.x; }
  else                      { g = g1; tile = blockIdx.x - s1; }
  __shared__ float sh[3 * 1056];        // 3 slots of 16 x 66
  const int tid = threadIdx.x, lane = tid & 63, kw = tid >> 6;
  const int l15 = lane & 15, kg = lane >> 4, kq = kg * 8, rq = kg * 4;
  const int m0 = (tile & 15) * 16;
  const int n0 = (tile >> 4) * 64;

  f32x4 c0{0.f,0.f,0.f,0.f}, c1 = c0, c2 = c0, c3 = c0;
  const bf16* __restrict__ ap = g.A + (size_t)(m0 + l15) * g.lda + kw * 256 + kq;
  const bf16* __restrict__ wp = g.W + (size_t)(n0 + l15) * 1024 + kw * 256 + kq;
  #pragma unroll
  for (int k = 0; k < 256; k += 32) {
    bf16x8 af = *(const bf16x8*)(ap + k);
    c0 = MF(af, *(const bf16x8*)(wp + k            ), c0);
    c1 = MF(af, *(const bf16x8*)(wp + 16 * 1024 + k), c1);
    c2 = MF(af, *(const bf16x8*)(wp + 32 * 1024 + k), c2);
    c3 = MF(af, *(const bf16x8*)(wp + 48 * 1024 + k), c3);
  }
  f32x4 cc[4] = {c0, c1, c2, c3};
  if (kw) {
    float* s = sh + (kw - 1) * 1056;
    #pragma unroll
    for (int t2 = 0; t2 < 4; ++t2)
      #pragma unroll
      for (int r = 0; r < 4; ++r)
        s[(rq + r) * 66 + t2 * 16 + l15] = cc[t2][r];
  }
  __syncthreads();
  if (kw == 0) {
    #pragma unroll
    for (int t2 = 0; t2 < 4; ++t2) {
      const int n = n0 + t2 * 16 + l15;
      const float bv = g.bias ? g.bias[n] : 0.f;
      #pragma unroll
      for (int r = 0; r < 4; ++r) {
        const int row = m0 + rq + r;
        float v = cc[t2][r] + bv;
        #pragma unroll
        for (int s = 0; s < 3; ++s)
          v += sh[s * 1056 + (rq + r) * 66 + t2 * 16 + l15];
        if (g.acc) v += g.acc[(size_t)row * g.accStride + n];
        if (g.relu) v = fmaxf(v, 0.f);
        if (g.outB) g.outB[(size_t)row * g.N + n] = (bf16)v;
        if (g.outF) g.outF[(size_t)row * g.N + n] = v;
      }
    }
  }
}

// ---------------- gi GEMM + GRU gates, split-K ----------------
// block (mt 0..15, cs 0..63): rows mt*16..+16, gate-cols cs*16..+16 of r/z/n.
__global__ __launch_bounds__(256, 4) void k_gates2(
    const bf16* __restrict__ x2b, const bf16* __restrict__ wihb,
    const float* __restrict__ bih, const float* __restrict__ gh,
    float* __restrict__ hf, bf16* __restrict__ hb, float* __restrict__ feat, int t) {
  __shared__ float sh[3 * 816];         // 3 slots x 3 gates x 16 x 17
  const int mt = blockIdx.x & 15, cs = blockIdx.x >> 4;
  const int tid = threadIdx.x, lane = tid & 63, kw = tid >> 6;
  const int l15 = lane & 15, kg = lane >> 4, kq = kg * 8, rq = kg * 4;

  f32x4 ar{0.f,0.f,0.f,0.f}, az = ar, an = ar;
  const bf16* __restrict__ ap = x2b + (size_t)(mt * 16 + l15) * 1024 + kw * 256 + kq;
  const bf16* __restrict__ wr = wihb + (size_t)(cs * 16 + l15) * 1024 + kw * 256 + kq;
  const size_t GOFF = (size_t)1024 * 1024;
  #pragma unroll
  for (int k = 0; k < 256; k += 32) {
    bf16x8 af = *(const bf16x8*)(ap + k);
    ar = MF(af, *(const bf16x8*)(wr + k           ), ar);
    az = MF(af, *(const bf16x8*)(wr + GOFF + k    ), az);
    an = MF(af, *(const bf16x8*)(wr + 2 * GOFF + k), an);
  }
  if (kw) {
    float* s = sh + (kw - 1) * 816;
    #pragma unroll
    for (int r = 0; r < 4; ++r) {
      s[(rq + r) * 17 + l15]             = ar[r];
      s[272 + (rq + r) * 17 + l15]       = az[r];
      s[544 + (rq + r) * 17 + l15]       = an[r];
    }
  }
  __syncthreads();
  if (kw == 0) {
    const int c = cs * 16 + l15;
    const float bir = bih[c], biz = bih[1024 + c], bin_ = bih[2048 + c];
    #pragma unroll
    for (int r = 0; r < 4; ++r) {
      float vr = ar[r], vz = az[r], vn = an[r];
      #pragma unroll
      for (int s = 0; s < 3; ++s) {
        vr += sh[s * 816 + (rq + r) * 17 + l15];
        vz += sh[s * 816 + 272 + (rq + r) * 17 + l15];
        vn += sh[s * 816 + 544 + (rq + r) * 17 + l15];
      }
      const int m = mt * 16 + rq + r;
      const float* ghp = gh + (size_t)m * 3072 + c;
      float rr = vr + bir + ghp[0];
      float zz = vz + biz + ghp[1024];
      const float hn = ghp[2048];
      rr = 1.f / (1.f + __expf(-rr));
      zz = 1.f / (1.f + __expf(-zz));
      const float nn = tanhf(vn + bin_ + rr * hn);
      const float h2 = (1.f - zz) * nn + zz * hf[(size_t)m * 1024 + c];
      hf[(size_t)m * 1024 + c] = h2;
      hb[(size_t)m * 1024 + c] = (bf16)h2;
      feat[((size_t)m * T_ + t) * 1056 + c] = h2;
    }
  }
}

// ---------------- heads + stats + z + feat_z + next x1 (16 blocks x 1024) ----------------
__global__ __launch_bounds__(1024, 1) void k_headfin2(
    const bf16* __restrict__ p2b, const bf16* __restrict__ q2b,
    const bf16* __restrict__ whead,            // [128,1024]: pr_m, pr_s, po_m, po_s
    const float* __restrict__ pr_mb, const float* __restrict__ pr_sb,
    const float* __restrict__ po_mb, const float* __restrict__ po_sb,
    const float* __restrict__ eps, const float* __restrict__ act,
    const float* __restrict__ in_w1, const float* __restrict__ in_b1,
    float* __restrict__ pm, float* __restrict__ ps,
    float* __restrict__ qm, float* __restrict__ qs,
    float* __restrict__ feat, bf16* __restrict__ x1b, int t) {
  __shared__ float sh[8 * 1056];        // 8 waves x 16 x 66
  __shared__ float zm[16][32], zs[16][32], zl[16][32], al[16][8];
  const int g = blockIdx.x, m0 = g * 16;
  const int tid = threadIdx.x, lane = tid & 63, w = tid >> 6;
  const int l15 = lane & 15, kg = lane >> 4, kq = kg * 8, rq = kg * 4;

  if (w < 8) {
    const int kw = w & 3, half = w >> 2;
    const bf16* __restrict__ A = half ? q2b : p2b;
    f32x4 c0{0.f,0.f,0.f,0.f}, c1 = c0, c2 = c0, c3 = c0;
    const bf16* __restrict__ ap = A + (size_t)(m0 + l15) * 1024 + kw * 256 + kq;
    const bf16* __restrict__ wp = whead + (size_t)(half * 64 + l15) * 1024 + kw * 256 + kq;
    #pragma unroll
    for (int k = 0; k < 256; k += 32) {
      bf16x8 af = *(const bf16x8*)(ap + k);
      c0 = MF(af, *(const bf16x8*)(wp + k            ), c0);
      c1 = MF(af, *(const bf16x8*)(wp + 16 * 1024 + k), c1);
      c2 = MF(af, *(const bf16x8*)(wp + 32 * 1024 + k), c2);
      c3 = MF(af, *(const bf16x8*)(wp + 48 * 1024 + k), c3);
    }
    f32x4 cc[4] = {c0, c1, c2, c3};
    float* s = sh + w * 1056;
    #pragma unroll
    for (int t2 = 0; t2 < 4; ++t2)
      #pragma unroll
      for (int r = 0; r < 4; ++r)
        s[(rq + r) * 66 + t2 * 16 + l15] = cc[t2][r];
  }
  if (tid >= 928 && tid < 1024) {       // 96 threads: load actions
    const int idx = tid - 928, r = idx / ACT_, k = idx - r * ACT_;
    al[r][k] = act[((size_t)(m0 + r) * T_ + t) * ACT_ + k];
  }
  __syncthreads();

  #pragma unroll
  for (int rep = 0; rep < 2; ++rep) {
    const int idx = rep * 1024 + tid;   // 0..2047 = 16 rows x 128 cols
    const int r = idx >> 7, c = idx & 127;
    const int base = (c < 64) ? 0 : 4, cl = c & 63;
    float v = sh[base * 1056 + r * 66 + cl] + sh[(base + 1) * 1056 + r * 66 + cl]
            + sh[(base + 2) * 1056 + r * 66 + cl] + sh[(base + 3) * 1056 + r * 66 + cl];
    const size_t ob = ((size_t)(m0 + r) * T_ + t) * STO_ + (c & 31);
    const int sel = c >> 5;
    if (sel == 0) {
      pm[ob] = v + pr_mb[c];
    } else if (sel == 1) {
      ps[ob] = __expf(fminf(fmaxf(v + pr_sb[c - 32], -5.f), 2.f));
    } else if (sel == 2) {
      const float x = v + po_mb[c - 64];
      qm[ob] = x; zm[r][c - 64] = x;
    } else {
      const float x = __expf(fminf(fmaxf(v + po_sb[c - 96], -5.f), 2.f));
      qs[ob] = x; zs[r][c - 96] = x;
    }
  }
  __syncthreads();
  if (tid < 512) {
    const int r = tid >> 5, j = tid & 31;
    const float z = zm[r][j] + zs[r][j] * eps[((size_t)(m0 + r) * T_ + t) * STO_ + j];
    zl[r][j] = z;
    feat[((size_t)(m0 + r) * T_ + t) * 1056 + 1024 + j] = z;
  }
  __syncthreads();

  // x1_{t+1}: each thread owns output col n=tid for all 16 rows; w1 row in regs.
  const int n = tid;
  float wv_[38];
  #pragma unroll
  for (int j = 0; j < 38; ++j) wv_[j] = in_w1[(size_t)n * 38 + j];
  const float bn = in_b1[n];
  #pragma unroll 2
  for (int r = 0; r < 16; ++r) {
    float a = bn;
    #pragma unroll
    for (int k = 0; k < STO_; ++k) a = fmaf(zl[r][k], wv_[k], a);
    #pragma unroll
    for (int k = 0; k < ACT_; ++k) a = fmaf(al[r][k], wv_[32 + k], a);
    x1b[(size_t)(m0 + r) * 1024 + n] = (bf16)fmaxf(a, 0.f);
  }
}

extern "C" void kernel_launch(void* const* d_in, const int* in_sizes, int n_in,
                              void* d_out, int out_size, void* d_ws, size_t ws_size,
                              hipStream_t stream) {
  (void)in_sizes; (void)n_in; (void)out_size; (void)ws_size;
  const float* obs      = (const float*)d_in[0];
  const float* actions  = (const float*)d_in[1];
  const float* eps_post = (const float*)d_in[3];   // eps_prior unused by the math
  const float* in_w1 = (const float*)d_in[4];
  const float* in_b1 = (const float*)d_in[5];
  const float* in_w2 = (const float*)d_in[6];
  const float* in_b2 = (const float*)d_in[7];
  const float* gru_wih = (const float*)d_in[8];
  const float* gru_whh = (const float*)d_in[9];
  const float* gru_bih = (const float*)d_in[10];
  const float* gru_bhh = (const float*)d_in[11];
  const float* pr_w1 = (const float*)d_in[12];
  const float* pr_b1 = (const float*)d_in[13];
  const float* pr_w2 = (const float*)d_in[14];
  const float* pr_b2 = (const float*)d_in[15];
  const float* pr_mw = (const float*)d_in[16];
  const float* pr_mb = (const float*)d_in[17];
  const float* pr_sw = (const float*)d_in[18];
  const float* pr_sb = (const float*)d_in[19];
  const float* po_w1 = (const float*)d_in[20];
  const float* po_b1 = (const float*)d_in[21];
  const float* po_w2 = (const float*)d_in[22];
  const float* po_b2 = (const float*)d_in[23];
  const float* po_mw = (const float*)d_in[24];
  const float* po_mb = (const float*)d_in[25];
  const float* po_sw = (const float*)d_in[26];
  const float* po_sb = (const float*)d_in[27];

  float* feat = (float*)d_out;
  float* pm = feat + (size_t)B_ * T_ * 1056;
  float* ps = pm + (size_t)B_ * T_ * STO_;
  float* qm = ps + (size_t)B_ * T_ * STO_;
  float* qs = qm + (size_t)B_ * T_ * STO_;

  char* wp_ = (char*)d_ws;
  auto carve = [&](size_t bytes) -> void* {
    void* r = (void*)wp_;
    wp_ += (bytes + 255) & ~(size_t)255;
    return r;
  };
  bf16* w_in2b  = (bf16*)carve((size_t)HID_ * HID_ * 2);
  bf16* w_wihb  = (bf16*)carve((size_t)3 * DET_ * HID_ * 2);
  bf16* w_whhb  = (bf16*)carve((size_t)3 * DET_ * DET_ * 2);
  bf16* w_pr1b  = (bf16*)carve((size_t)HID_ * DET_ * 2);
  bf16* w_pr2b  = (bf16*)carve((size_t)HID_ * HID_ * 2);
  bf16* w_po1hb = (bf16*)carve((size_t)HID_ * DET_ * 2);
  bf16* w_po1ob = (bf16*)carve((size_t)HID_ * OBS_ * 2);
  bf16* w_po2b  = (bf16*)carve((size_t)HID_ * HID_ * 2);
  bf16* w_headb = (bf16*)carve((size_t)128 * HID_ * 2);
  bf16* x1b  = (bf16*)carve((size_t)B_ * HID_ * 2);
  bf16* x2b  = (bf16*)carve((size_t)B_ * HID_ * 2);
  bf16* hb   = (bf16*)carve((size_t)B_ * DET_ * 2);
  bf16* p1b  = (bf16*)carve((size_t)B_ * HID_ * 2);
  bf16* q1b  = (bf16*)carve((size_t)B_ * HID_ * 2);
  bf16* p2b  = (bf16*)carve((size_t)B_ * HID_ * 2);
  bf16* q2b  = (bf16*)carve((size_t)B_ * HID_ * 2);
  float* hf       = (float*)carve((size_t)B_ * DET_ * 4);
  float* gh       = (float*)carve((size_t)B_ * 3 * DET_ * 4);
  float* q1acc    = (float*)carve((size_t)B_ * T_ * HID_ * 4);   // 64 MB

  // ---- prologue ----
  CvtArgs ca = { in_w2, gru_wih, gru_whh, pr_w1, pr_w2, po_w1, po_w2,
                 pr_mw, pr_sw, po_mw, po_sw,
                 w_in2b, w_wihb, w_whhb, w_pr1b, w_pr2b, w_po1hb, w_po1ob, w_po2b, w_headb };
  k_cvtall<<<dim3(12416), dim3(256), 0, stream>>>(ca);
  k_init<<<dim3(1024), dim3(256), 0, stream>>>(in_b1, x1b, hb, hf);
  k_qbatch<<<dim3(4096), dim3(256), 0, stream>>>(obs, w_po1ob, po_b1, q1acc);

  for (int t = 0; t < T_; ++t) {
    // K1: x2 (256 tiles) || gh (768 tiles)
    GB g_x2 = { x1b, w_in2b, in_b2,   nullptr, x2b, nullptr, 1024, 1024, 1, 0 };
    GB g_gh = { hb,  w_whhb, gru_bhh, nullptr, nullptr, gh, 3072, 1024, 0, 0 };
    k_mgs<<<dim3(1024), dim3(256), 0, stream>>>(g_x2, g_gh, 256);

    // K2: gi + GRU gates -> h, feat_h  (1024 blocks)
    k_gates2<<<dim3(1024), dim3(256), 0, stream>>>(x2b, w_wihb, gru_bih, gh, hf, hb, feat, t);

    // K3: pr1 (256) || q1 = relu(h@Wh + q1acc[:,t,:]) (256)
    GB g_pr1 = { hb, w_pr1b,  pr_b1,   nullptr,           p1b, nullptr, 1024, 1024, 1, 0 };
    GB g_q1  = { hb, w_po1hb, nullptr, q1acc + t * 1024,  q1b, nullptr, 1024, 1024, 1, T_ * 1024 };
    k_mgs<<<dim3(512), dim3(256), 0, stream>>>(g_pr1, g_q1, 256);

    // K4: pr2 (256) || po2 (256)
    GB g_pr2 = { p1b, w_pr2b, pr_b2, nullptr, p2b, nullptr, 1024, 1024, 1, 0 };
    GB g_po2 = { q1b, w_po2b, po_b2, nullptr, q2b, nullptr, 1024, 1024, 1, 0 };
    k_mgs<<<dim3(512), dim3(256), 0, stream>>>(g_pr2, g_po2, 256);

    // K5: all heads + stats + z + feat_z + next x1
    k_headfin2<<<dim3(16), dim3(1024), 0, stream>>>(
        p2b, q2b, w_headb, pr_mb, pr_sb, po_mb, po_sb,
        eps_post, actions, in_w1, in_b1, pm, ps, qm, qs, feat, x1b, t);
  }
}